// Round 16
// baseline (961.871 us; speedup 1.0000x reference)
//
#include <hip/hip_runtime.h>

#define NUM_TASKS 8
#define NUM_TABLES 16
#define HASH 1000000
#define BATCH 8192
#define NNZ (BATCH * 20)
#define OFF_ROW (BATCH + 1)
#define NPASS 16
#define RANGE (HASH / NPASS)        // 62500 (fits 16 bits)
#define CHUNK 640
#define NCHUNK (NNZ / CHUNK)        // 256
#define BCAP 12288                  // bucket capacity (mean 10240 + 20 sigma), 32-mult
#define SORT_STRIDE (NPASS * BCAP)  // 196608 per table
#define FS_CAP 11264                // finesort LDS capacity
#define NPG 4                       // pass-groups in gather (4 passes each)

// ws layout (bytes). No aliasing.
#define WS_PART  0ull                                   // [4pg][16t][8task][8192b] f32 = 16 MB
#define PART_BYTES ((size_t)NPG * NUM_TABLES * NUM_TASKS * BATCH * 4)     // 16,777,216
#define WS_SORT  PART_BYTES                             // [16t][16k][BCAP] u32 = 12.6 MB
#define SORT_BYTES ((size_t)NUM_TABLES * SORT_STRIDE * 4)
#define WS_CURS  (WS_SORT + SORT_BYTES)                 // [16t][16k] u32 cursors
#define WS_NEED  (WS_CURS + 1024ull)                    // ~29.4 MB

// ---------- 1) fused scatter: atomic-cursor bucket allocation ----------
// Replaces hist+scan+scatter (round 14 front-end): stability is unnecessary
// because finesort reorders by h anyway and accumulation-order jitter is
// already accepted (LDS float atomics, 3e-5 << 4.9e-4). One global atomicAdd
// per (bucket, wave-iteration) via ballot leader; fixed bucket bases k*BCAP.
__global__ void scatter_kernel(const int* __restrict__ indices, const int* __restrict__ offsets,
                               unsigned* __restrict__ sorted, unsigned* __restrict__ cursor)
{
    int w = threadIdx.x >> 6, lane = threadIdx.x & 63;
    int g = blockIdx.x * 4 + w;
    int t = g >> 8, chunk = g & 255;
    unsigned long long mlt = (1ull << lane) - 1ull;
    const int* off = offsets + t * OFF_ROW;
    const int* ip  = indices + (size_t)t * NNZ;
    unsigned* sp   = sorted + (size_t)t * SORT_STRIDE;
    unsigned* cur  = cursor + t * NPASS;

    for (int r = 0; r < CHUNK / 64; ++r) {
        int i = chunk * CHUNK + r * 64 + lane;
        int raw = ip[i];
        int k   = raw / RANGE;
        int hlo = raw - k * RANGE;
        int lo = 0, hi = BATCH;                 // bag: largest lo with off[lo] <= i
#pragma unroll
        for (int s = 0; s < 13; ++s) {
            int mid = (lo + hi) >> 1;
            if (off[mid] <= i) lo = mid; else hi = mid;
        }
        unsigned pos = 0;
#pragma unroll
        for (int kk = 0; kk < NPASS; ++kk) {
            unsigned long long m = __ballot(k == kk);
            if (m) {
                int leader = __ffsll((long long)m) - 1;
                unsigned base = 0;
                if (lane == leader) base = atomicAdd(&cur[kk], (unsigned)__popcll(m));
                base = (unsigned)__shfl((int)base, leader, 64);
                if (k == kk) pos = base + (unsigned)__popcll(m & mlt);
            }
        }
        sp[(unsigned)k * BCAP + pos] = ((unsigned)hlo << 16) | (unsigned)lo;
    }
}

// ---------- 2) fine sort: per (t,k) bucket, 256-way counting sort on h_lo>>8 ----------
__global__ __launch_bounds__(256)
void finesort_kernel(unsigned* __restrict__ sorted, const unsigned* __restrict__ cursor)
{
    __shared__ unsigned ebuf[FS_CAP];         // 44 KB
    __shared__ unsigned hcnt[256];
    __shared__ unsigned hstart[256];
    int tk = blockIdx.x;                      // t*16 + k
    int t = tk >> 4, k = tk & 15;
    unsigned n = cursor[tk];
    unsigned* sp = sorted + (size_t)t * SORT_STRIDE + (unsigned)k * BCAP;
    int tid = threadIdx.x;
    if (n > FS_CAP) return;                   // leave unsorted (still correct)

    hcnt[tid] = 0;
    __syncthreads();
    for (unsigned i = tid; i < n; i += 256) {
        unsigned e = sp[i];
        ebuf[i] = e;
        atomicAdd(&hcnt[e >> 24], 1u);        // e>>24 = h_lo>>8
    }
    __syncthreads();
    if (tid == 0) {
        unsigned run = 0;
        for (int j = 0; j < 256; ++j) { hstart[j] = run; run += hcnt[j]; }
    }
    __syncthreads();
    hcnt[tid] = 0;                            // reuse as cursor
    __syncthreads();
    for (unsigned i = tid; i < n; i += 256) {
        unsigned e = ebuf[i];
        unsigned sb = e >> 24;
        unsigned pos = hstart[sb] + atomicAdd(&hcnt[sb], 1u);
        sp[pos] = e;
    }
}

// ---------- 3) h-major gather (round-14 proven shape: task-major bid, uint2) ----------
__global__ __launch_bounds__(1024)
void gather_kernel(const float* __restrict__ W, const unsigned* __restrict__ sorted,
                   const unsigned* __restrict__ cursor, float* __restrict__ partial)
{
    __shared__ float accum[BATCH];            // 32 KB (2 blocks/CU -> 64 KB/CU)
    const int bid  = blockIdx.x;              // 512 = 4pg * 16t * 8task
    const int task = bid & 7;
    const int t    = (bid >> 3) & 15;
    const int pg   = bid >> 7;
    const int tid  = threadIdx.x;

    float4* av = (float4*)accum;
    float4 z4 = make_float4(0.f, 0.f, 0.f, 0.f);
    av[tid]        = z4;
    av[tid + 1024] = z4;
    __syncthreads();

    const float* Wbase = W + ((size_t)task * NUM_TABLES + t) * HASH;

#pragma unroll 1
    for (int j = 0; j < NPASS / NPG; ++j) {
        const int p = pg * (NPASS / NPG) + j;
        const unsigned n = cursor[t * NPASS + p];
        const unsigned* ep = sorted + (size_t)t * SORT_STRIDE + (unsigned)p * BCAP;
        const float* Wt = Wbase + (size_t)p * RANGE;
        const uint2* ep2 = (const uint2*)ep;  // BCAP*4B is 8B-aligned
        const unsigned npair = n >> 1;
        for (unsigned i = tid; i < npair; i += 1024) {
            uint2 e = ep2[i];
            float v0 = Wt[e.x >> 16];
            float v1 = Wt[e.y >> 16];
            atomicAdd(&accum[e.x & 0xFFFFu], v0);
            atomicAdd(&accum[e.y & 0xFFFFu], v1);
        }
        if (tid == 0 && (n & 1u)) {
            unsigned e = ep[n - 1];
            atomicAdd(&accum[e & 0xFFFFu], Wt[e >> 16]);
        }
    }
    __syncthreads();

    float4* pp = (float4*)(partial + (((size_t)(pg * NUM_TABLES + t) * NUM_TASKS) + task) * BATCH);
    pp[tid]        = av[tid];
    pp[tid + 1024] = av[tid + 1024];
}

// ---------- 4) reduce 4 pass-groups (coalesced) ----------
__global__ void reduce_kernel(const float* __restrict__ partial, float* __restrict__ out)
{
    int tid  = blockIdx.x * blockDim.x + threadIdx.x;   // 65536 threads
    int task = tid >> 13;                               // 0..7
    int b    = tid & (BATCH - 1);

    float s[NUM_TABLES];
#pragma unroll
    for (int t = 0; t < NUM_TABLES; ++t) {
        float a = 0.f;
#pragma unroll
        for (int pg = 0; pg < NPG; ++pg)
            a += partial[(((size_t)(pg * NUM_TABLES + t) * NUM_TASKS) + task) * BATCH + b];
        s[t] = a;
    }

    float4* o = (float4*)(out + ((size_t)task * BATCH + b) * NUM_TABLES);
    o[0] = make_float4(s[0],  s[1],  s[2],  s[3]);
    o[1] = make_float4(s[4],  s[5],  s[6],  s[7]);
    o[2] = make_float4(s[8],  s[9],  s[10], s[11]);
    o[3] = make_float4(s[12], s[13], s[14], s[15]);
}

// ---------- fallback (round-3 kernel) if ws is too small ----------
__global__ void pool_fallback_kernel(const float* __restrict__ W, const int* __restrict__ offsets,
                                     const int* __restrict__ indices, float* __restrict__ out)
{
    const int block = blockIdx.x;
    const int t        = block >> 11;
    const int bag_base = (block & 2047) << 2;
    const int wave     = threadIdx.x >> 6;
    const int b        = bag_base + wave;
    const int lane     = threadIdx.x & 63;
    const int task     = lane & 7;
    const int split    = lane >> 3;
    const int start = offsets[t * OFF_ROW + b];
    const int end   = offsets[t * OFF_ROW + b + 1];
    const int*   idxp   = indices + (size_t)t * NNZ;
    const float* Wslice = W + ((size_t)task * NUM_TABLES + t) * (size_t)HASH;
    float acc = 0.0f;
    for (int i = start + split; i < end; i += 8) acc += Wslice[idxp[i]];
    acc += __shfl_xor(acc, 8); acc += __shfl_xor(acc, 16); acc += __shfl_xor(acc, 32);
    if (split == 0) out[((size_t)task * BATCH + b) * NUM_TABLES + t] = acc;
}

extern "C" void kernel_launch(void* const* d_in, const int* in_sizes, int n_in,
                              void* d_out, int out_size, void* d_ws, size_t ws_size,
                              hipStream_t stream) {
    const float* W       = (const float*)d_in[0];
    const int*   offsets = (const int*)d_in[1];
    const int*   indices = (const int*)d_in[2];
    float*       out     = (float*)d_out;

    if (ws_size < WS_NEED) {
        pool_fallback_kernel<<<NUM_TABLES * 2048, 256, 0, stream>>>(W, offsets, indices, out);
        return;
    }

    float*    partial = (float*)((char*)d_ws + WS_PART);
    unsigned* sorted  = (unsigned*)((char*)d_ws + WS_SORT);
    unsigned* cursor  = (unsigned*)((char*)d_ws + WS_CURS);

    hipMemsetAsync(cursor, 0, NUM_TABLES * NPASS * sizeof(unsigned), stream);
    scatter_kernel<<<(NUM_TABLES * NCHUNK) / 4, 256, 0, stream>>>(indices, offsets, sorted, cursor);
    finesort_kernel<<<NUM_TABLES * NPASS, 256, 0, stream>>>(sorted, cursor);
    gather_kernel<<<NPG * NUM_TABLES * NUM_TASKS, 1024, 0, stream>>>(W, sorted, cursor, partial);
    reduce_kernel<<<(NUM_TASKS * BATCH) / 256, 256, 0, stream>>>(partial, out);
}

// Round 17
// 195.764 us; speedup vs baseline: 4.9134x; 4.9134x over previous
//
#include <hip/hip_runtime.h>

#define NUM_TASKS 8
#define NUM_TABLES 16
#define HASH 1000000
#define BATCH 8192
#define NNZ (BATCH * 20)
#define OFF_ROW (BATCH + 1)
#define NPASS 16
#define RANGE (HASH / NPASS)        // 62500 (fits 16 bits)
#define CHUNK 640
#define NCHUNK (NNZ / CHUNK)        // 256
#define SORT_STRIDE (NNZ + 512)
#define FS_CAP 11264                // finesort LDS capacity (mean 10240, +10 sigma)
#define NPG 4                       // pass-groups in gather (4 passes each)

// ws layout (bytes). No aliasing.
#define WS_PART  0ull                                   // [4pg][16t][8task][8192b] f32 = 16 MB
#define PART_BYTES ((size_t)NPG * NUM_TABLES * NUM_TASKS * BATCH * 4)     // 16,777,216
#define WS_SORT  PART_BYTES                             // [16t][SORT_STRIDE] u32 = 10.5 MB
#define SORT_BYTES ((size_t)NUM_TABLES * SORT_STRIDE * 4)
#define WS_HIST  (WS_SORT + SORT_BYTES)                 // [16t][16k][256c] u32 = 256 KB
#define WS_BB    (WS_HIST + 262144ull)                  // [16t][16k] u32
#define WS_CNTB  (WS_BB + 1024ull)                      // [16t][16k] u32
#define WS_NEED  (WS_CNTB + 1024ull)                    // ~28 MB

// ---------- 1) per-chunk histogram ----------
__global__ void hist_kernel(const int* __restrict__ indices, unsigned* __restrict__ hist)
{
    __shared__ int h[4][NPASS];
    int w = threadIdx.x >> 6, lane = threadIdx.x & 63;
    int g = blockIdx.x * 4 + w;
    int t = g >> 8, chunk = g & 255;
    if (lane < NPASS) h[w][lane] = 0;
    __syncthreads();
    const int* ip = indices + (size_t)t * NNZ + chunk * CHUNK;
    for (int r = 0; r < CHUNK / 64; ++r) {
        int k = ip[r * 64 + lane] / RANGE;
        atomicAdd(&h[w][k], 1);
    }
    __syncthreads();
    if (lane < NPASS) hist[((size_t)t * NPASS + lane) * NCHUNK + chunk] = (unsigned)h[w][lane];
}

// ---------- 2) scan: per-(t,k) exclusive chunk scan + 32-aligned bucket bases ----------
__global__ void scan_kernel(unsigned* __restrict__ hist, unsigned* __restrict__ bb, unsigned* __restrict__ cnt)
{
    int t = blockIdx.x, tid = threadIdx.x;
    __shared__ unsigned tot[NPASS];
    if (tid < NPASS) {
        unsigned run = 0;
        unsigned* hp = hist + ((size_t)t * NPASS + tid) * NCHUNK;
        for (int c = 0; c < NCHUNK; ++c) { unsigned v = hp[c]; hp[c] = run; run += v; }
        tot[tid] = run;
        cnt[t * NPASS + tid] = run;
    }
    __syncthreads();
    if (tid == 0) {
        unsigned base = 0;
        for (int k = 0; k < NPASS; ++k) { bb[t * NPASS + k] = base; base += (tot[k] + 31u) & ~31u; }
    }
}

// ---------- 3) stable scatter: pack (h_lo<<16 | bag) into 16 h-range buckets ----------
__global__ void scatter_kernel(const int* __restrict__ indices, const int* __restrict__ offsets,
                               const unsigned* __restrict__ hist, const unsigned* __restrict__ bb,
                               unsigned* __restrict__ sorted)
{
    int w = threadIdx.x >> 6, lane = threadIdx.x & 63;
    int g = blockIdx.x * 4 + w;
    int t = g >> 8, chunk = g & 255;
    unsigned cur = 0;
    if (lane < NPASS)
        cur = bb[t * NPASS + lane] + hist[((size_t)t * NPASS + lane) * NCHUNK + chunk];
    unsigned long long mlt = (1ull << lane) - 1ull;
    const int* off = offsets + t * OFF_ROW;
    const int* ip  = indices + (size_t)t * NNZ;
    unsigned* sp   = sorted + (size_t)t * SORT_STRIDE;

    for (int r = 0; r < CHUNK / 64; ++r) {
        int i = chunk * CHUNK + r * 64 + lane;
        int raw = ip[i];
        int k   = raw / RANGE;
        int hlo = raw - k * RANGE;
        int lo = 0, hi = BATCH;                 // bag: largest lo with off[lo] <= i
#pragma unroll
        for (int s = 0; s < 13; ++s) {
            int mid = (lo + hi) >> 1;
            if (off[mid] <= i) lo = mid; else hi = mid;
        }
        unsigned pos = 0;
#pragma unroll
        for (int kk = 0; kk < NPASS; ++kk) {
            unsigned long long m = __ballot(k == kk);
            unsigned bc = (unsigned)__shfl((int)cur, kk, 64);
            if (k == kk) pos = bc + (unsigned)__popcll(m & mlt);
            if (lane == kk) cur += (unsigned)__popcll(m);
        }
        sp[pos] = ((unsigned)hlo << 16) | (unsigned)lo;
    }
}

// ---------- 4) fine sort: per (t,k) bucket, 256-way counting sort on h_lo>>8 ----------
__global__ __launch_bounds__(256)
void finesort_kernel(unsigned* __restrict__ sorted, const unsigned* __restrict__ bb,
                     const unsigned* __restrict__ cnt)
{
    __shared__ unsigned ebuf[FS_CAP];         // 44 KB
    __shared__ unsigned hcnt[256];
    __shared__ unsigned hstart[256];
    int tk = blockIdx.x;                      // t*16 + k
    int t = tk >> 4;
    unsigned n = cnt[tk];
    unsigned* sp = sorted + (size_t)t * SORT_STRIDE + bb[tk];
    int tid = threadIdx.x;
    if (n > FS_CAP) return;                   // leave bag-ordered (still correct)

    hcnt[tid] = 0;
    __syncthreads();
    for (unsigned i = tid; i < n; i += 256) {
        unsigned e = sp[i];
        ebuf[i] = e;
        atomicAdd(&hcnt[e >> 24], 1u);        // e>>24 = h_lo>>8
    }
    __syncthreads();
    if (tid == 0) {
        unsigned run = 0;
        for (int j = 0; j < 256; ++j) { hstart[j] = run; run += hcnt[j]; }
    }
    __syncthreads();
    hcnt[tid] = 0;                            // reuse as cursor
    __syncthreads();
    for (unsigned i = tid; i < n; i += 256) {
        unsigned e = ebuf[i];
        unsigned sb = e >> 24;
        unsigned pos = hstart[sb] + atomicAdd(&hcnt[sb], 1u);
        sp[pos] = e;
    }
}

// ---------- 5) h-major gather (round-14 shape + 2x unrolled uint2 = ILP4) ----------
// ONLY change vs round 14 (194 us measured): the pair loop issues TWO uint2
// entry loads up front -> 4 independent W loads in flight per thread-iter
// (was 2). Little's law says round 14's ~4.4 TB/s effective was concurrency-
// limited; this doubles outstanding requests. bid mapping, NPG, accum, tail
// all unchanged.
__global__ __launch_bounds__(1024)
void gather_kernel(const float* __restrict__ W, const unsigned* __restrict__ sorted,
                   const unsigned* __restrict__ bb, const unsigned* __restrict__ cnt,
                   float* __restrict__ partial)
{
    __shared__ float accum[BATCH];            // 32 KB (2 blocks/CU -> 64 KB/CU)
    const int bid  = blockIdx.x;              // 512 = 4pg * 16t * 8task
    const int task = bid & 7;
    const int t    = (bid >> 3) & 15;
    const int pg   = bid >> 7;
    const int tid  = threadIdx.x;

    float4* av = (float4*)accum;
    float4 z4 = make_float4(0.f, 0.f, 0.f, 0.f);
    av[tid]        = z4;
    av[tid + 1024] = z4;
    __syncthreads();

    const float* Wbase = W + ((size_t)task * NUM_TABLES + t) * HASH;

#pragma unroll 1
    for (int j = 0; j < NPASS / NPG; ++j) {
        const int p = pg * (NPASS / NPG) + j;
        const unsigned n = cnt[t * NPASS + p];
        const unsigned* ep = sorted + (size_t)t * SORT_STRIDE + bb[t * NPASS + p];
        const float* Wt = Wbase + (size_t)p * RANGE;
        const uint2* ep2 = (const uint2*)ep;  // buckets 32-aligned -> 8B aligned
        const unsigned npair = n >> 1;
        unsigned i = tid;
        for (; i + 1024 < npair; i += 2048) {
            uint2 e0 = ep2[i];
            uint2 e1 = ep2[i + 1024];
            float v0 = Wt[e0.x >> 16];
            float v1 = Wt[e0.y >> 16];
            float v2 = Wt[e1.x >> 16];
            float v3 = Wt[e1.y >> 16];
            atomicAdd(&accum[e0.x & 0xFFFFu], v0);
            atomicAdd(&accum[e0.y & 0xFFFFu], v1);
            atomicAdd(&accum[e1.x & 0xFFFFu], v2);
            atomicAdd(&accum[e1.y & 0xFFFFu], v3);
        }
        for (; i < npair; i += 1024) {
            uint2 e = ep2[i];
            float v0 = Wt[e.x >> 16];
            float v1 = Wt[e.y >> 16];
            atomicAdd(&accum[e.x & 0xFFFFu], v0);
            atomicAdd(&accum[e.y & 0xFFFFu], v1);
        }
        if (tid == 0 && (n & 1u)) {
            unsigned e = ep[n - 1];
            atomicAdd(&accum[e & 0xFFFFu], Wt[e >> 16]);
        }
    }
    __syncthreads();

    float4* pp = (float4*)(partial + (((size_t)(pg * NUM_TABLES + t) * NUM_TASKS) + task) * BATCH);
    pp[tid]        = av[tid];
    pp[tid + 1024] = av[tid + 1024];
}

// ---------- 6) reduce 4 pass-groups (coalesced) ----------
__global__ void reduce_kernel(const float* __restrict__ partial, float* __restrict__ out)
{
    int tid  = blockIdx.x * blockDim.x + threadIdx.x;   // 65536 threads
    int task = tid >> 13;                               // 0..7
    int b    = tid & (BATCH - 1);

    float s[NUM_TABLES];
#pragma unroll
    for (int t = 0; t < NUM_TABLES; ++t) {
        float a = 0.f;
#pragma unroll
        for (int pg = 0; pg < NPG; ++pg)
            a += partial[(((size_t)(pg * NUM_TABLES + t) * NUM_TASKS) + task) * BATCH + b];
        s[t] = a;
    }

    float4* o = (float4*)(out + ((size_t)task * BATCH + b) * NUM_TABLES);
    o[0] = make_float4(s[0],  s[1],  s[2],  s[3]);
    o[1] = make_float4(s[4],  s[5],  s[6],  s[7]);
    o[2] = make_float4(s[8],  s[9],  s[10], s[11]);
    o[3] = make_float4(s[12], s[13], s[14], s[15]);
}

// ---------- fallback (round-3 kernel) if ws is too small ----------
__global__ void pool_fallback_kernel(const float* __restrict__ W, const int* __restrict__ offsets,
                                     const int* __restrict__ indices, float* __restrict__ out)
{
    const int block = blockIdx.x;
    const int t        = block >> 11;
    const int bag_base = (block & 2047) << 2;
    const int wave     = threadIdx.x >> 6;
    const int b        = bag_base + wave;
    const int lane     = threadIdx.x & 63;
    const int task     = lane & 7;
    const int split    = lane >> 3;
    const int start = offsets[t * OFF_ROW + b];
    const int end   = offsets[t * OFF_ROW + b + 1];
    const int*   idxp   = indices + (size_t)t * NNZ;
    const float* Wslice = W + ((size_t)task * NUM_TABLES + t) * (size_t)HASH;
    float acc = 0.0f;
    for (int i = start + split; i < end; i += 8) acc += Wslice[idxp[i]];
    acc += __shfl_xor(acc, 8); acc += __shfl_xor(acc, 16); acc += __shfl_xor(acc, 32);
    if (split == 0) out[((size_t)task * BATCH + b) * NUM_TABLES + t] = acc;
}

extern "C" void kernel_launch(void* const* d_in, const int* in_sizes, int n_in,
                              void* d_out, int out_size, void* d_ws, size_t ws_size,
                              hipStream_t stream) {
    const float* W       = (const float*)d_in[0];
    const int*   offsets = (const int*)d_in[1];
    const int*   indices = (const int*)d_in[2];
    float*       out     = (float*)d_out;

    if (ws_size < WS_NEED) {
        pool_fallback_kernel<<<NUM_TABLES * 2048, 256, 0, stream>>>(W, offsets, indices, out);
        return;
    }

    float*    partial = (float*)((char*)d_ws + WS_PART);
    unsigned* sorted  = (unsigned*)((char*)d_ws + WS_SORT);
    unsigned* hist    = (unsigned*)((char*)d_ws + WS_HIST);
    unsigned* bb      = (unsigned*)((char*)d_ws + WS_BB);
    unsigned* cntb    = (unsigned*)((char*)d_ws + WS_CNTB);

    hist_kernel<<<(NUM_TABLES * NCHUNK) / 4, 256, 0, stream>>>(indices, hist);
    scan_kernel<<<NUM_TABLES, 64, 0, stream>>>(hist, bb, cntb);
    scatter_kernel<<<(NUM_TABLES * NCHUNK) / 4, 256, 0, stream>>>(indices, offsets, hist, bb, sorted);
    finesort_kernel<<<NUM_TABLES * NPASS, 256, 0, stream>>>(sorted, bb, cntb);
    gather_kernel<<<NPG * NUM_TABLES * NUM_TASKS, 1024, 0, stream>>>(W, sorted, bb, cntb, partial);
    reduce_kernel<<<(NUM_TASKS * BATCH) / 256, 256, 0, stream>>>(partial, out);
}

// Round 18
// 190.300 us; speedup vs baseline: 5.0545x; 1.0287x over previous
//
#include <hip/hip_runtime.h>

#define NUM_TASKS 8
#define NUM_TABLES 16
#define HASH 1000000
#define BATCH 8192
#define NNZ (BATCH * 20)
#define OFF_ROW (BATCH + 1)
#define NPASS 16
#define RANGE (HASH / NPASS)        // 62500 (fits 16 bits)
#define CHUNK 640
#define NCHUNK (NNZ / CHUNK)        // 256
#define SORT_STRIDE (NNZ + 512)
#define FS_CAP 11264                // finesort LDS capacity (mean 10240, +10 sigma)
#define NPG 4                       // pass-groups in gather (4 passes each)

// ws layout (bytes). No aliasing.
#define WS_PART  0ull                                   // [4pg][16t][8task][8192b] f32 = 16 MB
#define PART_BYTES ((size_t)NPG * NUM_TABLES * NUM_TASKS * BATCH * 4)     // 16,777,216
#define WS_SORT  PART_BYTES                             // [16t][SORT_STRIDE] u32 = 10.5 MB
#define SORT_BYTES ((size_t)NUM_TABLES * SORT_STRIDE * 4)
#define WS_SEG   (WS_SORT + SORT_BYTES)                 // [16t][NNZ] u32 = 10.5 MB
#define SEG_BYTES ((size_t)NUM_TABLES * NNZ * 4)
#define WS_HIST  (WS_SEG + SEG_BYTES)                   // [16t][16k][256c] u32 = 256 KB
#define WS_BB    (WS_HIST + 262144ull)                  // [16t][16k] u32
#define WS_CNTB  (WS_BB + 1024ull)                      // [16t][16k] u32
#define WS_NEED  (WS_CNTB + 1024ull)                    // ~38 MB

// ---------- 1) per-chunk histogram + seg-id build ----------
// Spare-thread fusion: besides the 4 chunk-wave histograms, each thread
// (first 131072 of 262144) owns one bag and writes seg[t][i]=b over its
// offset range — adjacent threads write adjacent ranges (write-combines in
// L2). This seg array replaces the scatter's 13-iteration binary search
// (13 DEPENDENT ~200-cyc L2 loads per entry, the scatter's critical path).
__global__ void hist_kernel(const int* __restrict__ indices, const int* __restrict__ offsets,
                            unsigned* __restrict__ hist, unsigned* __restrict__ seg)
{
    // ---- seg build: one bag per thread (131072 bags, 262144 threads) ----
    int bag_gid = blockIdx.x * 256 + (int)threadIdx.x;
    if (bag_gid < NUM_TABLES * BATCH) {
        int bt = bag_gid >> 13;
        int b  = bag_gid & (BATCH - 1);
        int s  = offsets[bt * OFF_ROW + b];
        int e  = offsets[bt * OFF_ROW + b + 1];
        unsigned* sg = seg + (size_t)bt * NNZ;
        for (int i = s; i < e; ++i) sg[i] = (unsigned)b;
    }

    // ---- histogram (unchanged) ----
    __shared__ int h[4][NPASS];
    int w = threadIdx.x >> 6, lane = threadIdx.x & 63;
    int g = blockIdx.x * 4 + w;
    int t = g >> 8, chunk = g & 255;
    if (lane < NPASS) h[w][lane] = 0;
    __syncthreads();
    const int* ip = indices + (size_t)t * NNZ + chunk * CHUNK;
    for (int r = 0; r < CHUNK / 64; ++r) {
        int k = ip[r * 64 + lane] / RANGE;
        atomicAdd(&h[w][k], 1);
    }
    __syncthreads();
    if (lane < NPASS) hist[((size_t)t * NPASS + lane) * NCHUNK + chunk] = (unsigned)h[w][lane];
}

// ---------- 2) scan: per-(t,k) exclusive chunk scan + 32-aligned bucket bases ----------
__global__ void scan_kernel(unsigned* __restrict__ hist, unsigned* __restrict__ bb, unsigned* __restrict__ cnt)
{
    int t = blockIdx.x, tid = threadIdx.x;
    __shared__ unsigned tot[NPASS];
    if (tid < NPASS) {
        unsigned run = 0;
        unsigned* hp = hist + ((size_t)t * NPASS + tid) * NCHUNK;
        for (int c = 0; c < NCHUNK; ++c) { unsigned v = hp[c]; hp[c] = run; run += v; }
        tot[tid] = run;
        cnt[t * NPASS + tid] = run;
    }
    __syncthreads();
    if (tid == 0) {
        unsigned base = 0;
        for (int k = 0; k < NPASS; ++k) { bb[t * NPASS + k] = base; base += (tot[k] + 31u) & ~31u; }
    }
}

// ---------- 3) stable scatter: seg-id lookup instead of binary search ----------
__global__ void scatter_kernel(const int* __restrict__ indices, const unsigned* __restrict__ seg,
                               const unsigned* __restrict__ hist, const unsigned* __restrict__ bb,
                               unsigned* __restrict__ sorted)
{
    int w = threadIdx.x >> 6, lane = threadIdx.x & 63;
    int g = blockIdx.x * 4 + w;
    int t = g >> 8, chunk = g & 255;
    unsigned cur = 0;
    if (lane < NPASS)
        cur = bb[t * NPASS + lane] + hist[((size_t)t * NPASS + lane) * NCHUNK + chunk];
    unsigned long long mlt = (1ull << lane) - 1ull;
    const int* ip      = indices + (size_t)t * NNZ;
    const unsigned* sg = seg + (size_t)t * NNZ;
    unsigned* sp       = sorted + (size_t)t * SORT_STRIDE;

    for (int r = 0; r < CHUNK / 64; ++r) {
        int i = chunk * CHUNK + r * 64 + lane;
        int raw = ip[i];
        unsigned lo = sg[i];                    // coalesced, replaces 13-step search
        int k   = raw / RANGE;
        int hlo = raw - k * RANGE;
        unsigned pos = 0;
#pragma unroll
        for (int kk = 0; kk < NPASS; ++kk) {
            unsigned long long m = __ballot(k == kk);
            unsigned bc = (unsigned)__shfl((int)cur, kk, 64);
            if (k == kk) pos = bc + (unsigned)__popcll(m & mlt);
            if (lane == kk) cur += (unsigned)__popcll(m);
        }
        sp[pos] = ((unsigned)hlo << 16) | lo;
    }
}

// ---------- 4) fine sort: per (t,k) bucket, 256-way counting sort on h_lo>>8 ----------
__global__ __launch_bounds__(256)
void finesort_kernel(unsigned* __restrict__ sorted, const unsigned* __restrict__ bb,
                     const unsigned* __restrict__ cnt)
{
    __shared__ unsigned ebuf[FS_CAP];         // 44 KB
    __shared__ unsigned hcnt[256];
    __shared__ unsigned hstart[256];
    int tk = blockIdx.x;                      // t*16 + k
    int t = tk >> 4;
    unsigned n = cnt[tk];
    unsigned* sp = sorted + (size_t)t * SORT_STRIDE + bb[tk];
    int tid = threadIdx.x;
    if (n > FS_CAP) return;                   // leave bag-ordered (still correct)

    hcnt[tid] = 0;
    __syncthreads();
    for (unsigned i = tid; i < n; i += 256) {
        unsigned e = sp[i];
        ebuf[i] = e;
        atomicAdd(&hcnt[e >> 24], 1u);        // e>>24 = h_lo>>8
    }
    __syncthreads();
    if (tid == 0) {
        unsigned run = 0;
        for (int j = 0; j < 256; ++j) { hstart[j] = run; run += hcnt[j]; }
    }
    __syncthreads();
    hcnt[tid] = 0;                            // reuse as cursor
    __syncthreads();
    for (unsigned i = tid; i < n; i += 256) {
        unsigned e = ebuf[i];
        unsigned sb = e >> 24;
        unsigned pos = hstart[sb] + atomicAdd(&hcnt[sb], 1u);
        sp[pos] = e;
    }
}

// ---------- 5) h-major gather (round-14 proven shape, unchanged) ----------
__global__ __launch_bounds__(1024)
void gather_kernel(const float* __restrict__ W, const unsigned* __restrict__ sorted,
                   const unsigned* __restrict__ bb, const unsigned* __restrict__ cnt,
                   float* __restrict__ partial)
{
    __shared__ float accum[BATCH];            // 32 KB (2 blocks/CU -> 64 KB/CU)
    const int bid  = blockIdx.x;              // 512 = 4pg * 16t * 8task
    const int task = bid & 7;
    const int t    = (bid >> 3) & 15;
    const int pg   = bid >> 7;
    const int tid  = threadIdx.x;

    float4* av = (float4*)accum;
    float4 z4 = make_float4(0.f, 0.f, 0.f, 0.f);
    av[tid]        = z4;
    av[tid + 1024] = z4;
    __syncthreads();

    const float* Wbase = W + ((size_t)task * NUM_TABLES + t) * HASH;

#pragma unroll 1
    for (int j = 0; j < NPASS / NPG; ++j) {
        const int p = pg * (NPASS / NPG) + j;
        const unsigned n = cnt[t * NPASS + p];
        const unsigned* ep = sorted + (size_t)t * SORT_STRIDE + bb[t * NPASS + p];
        const float* Wt = Wbase + (size_t)p * RANGE;
        const uint2* ep2 = (const uint2*)ep;  // buckets 32-aligned -> 8B aligned
        const unsigned npair = n >> 1;
        for (unsigned i = tid; i < npair; i += 1024) {
            uint2 e = ep2[i];
            float v0 = Wt[e.x >> 16];
            float v1 = Wt[e.y >> 16];
            atomicAdd(&accum[e.x & 0xFFFFu], v0);
            atomicAdd(&accum[e.y & 0xFFFFu], v1);
        }
        if (tid == 0 && (n & 1u)) {
            unsigned e = ep[n - 1];
            atomicAdd(&accum[e & 0xFFFFu], Wt[e >> 16]);
        }
    }
    __syncthreads();

    float4* pp = (float4*)(partial + (((size_t)(pg * NUM_TABLES + t) * NUM_TASKS) + task) * BATCH);
    pp[tid]        = av[tid];
    pp[tid + 1024] = av[tid + 1024];
}

// ---------- 6) reduce 4 pass-groups (coalesced) ----------
__global__ void reduce_kernel(const float* __restrict__ partial, float* __restrict__ out)
{
    int tid  = blockIdx.x * blockDim.x + threadIdx.x;   // 65536 threads
    int task = tid >> 13;                               // 0..7
    int b    = tid & (BATCH - 1);

    float s[NUM_TABLES];
#pragma unroll
    for (int t = 0; t < NUM_TABLES; ++t) {
        float a = 0.f;
#pragma unroll
        for (int pg = 0; pg < NPG; ++pg)
            a += partial[(((size_t)(pg * NUM_TABLES + t) * NUM_TASKS) + task) * BATCH + b];
        s[t] = a;
    }

    float4* o = (float4*)(out + ((size_t)task * BATCH + b) * NUM_TABLES);
    o[0] = make_float4(s[0],  s[1],  s[2],  s[3]);
    o[1] = make_float4(s[4],  s[5],  s[6],  s[7]);
    o[2] = make_float4(s[8],  s[9],  s[10], s[11]);
    o[3] = make_float4(s[12], s[13], s[14], s[15]);
}

// ---------- fallback (round-3 kernel) if ws is too small ----------
__global__ void pool_fallback_kernel(const float* __restrict__ W, const int* __restrict__ offsets,
                                     const int* __restrict__ indices, float* __restrict__ out)
{
    const int block = blockIdx.x;
    const int t        = block >> 11;
    const int bag_base = (block & 2047) << 2;
    const int wave     = threadIdx.x >> 6;
    const int b        = bag_base + wave;
    const int lane     = threadIdx.x & 63;
    const int task     = lane & 7;
    const int split    = lane >> 3;
    const int start = offsets[t * OFF_ROW + b];
    const int end   = offsets[t * OFF_ROW + b + 1];
    const int*   idxp   = indices + (size_t)t * NNZ;
    const float* Wslice = W + ((size_t)task * NUM_TABLES + t) * (size_t)HASH;
    float acc = 0.0f;
    for (int i = start + split; i < end; i += 8) acc += Wslice[idxp[i]];
    acc += __shfl_xor(acc, 8); acc += __shfl_xor(acc, 16); acc += __shfl_xor(acc, 32);
    if (split == 0) out[((size_t)task * BATCH + b) * NUM_TABLES + t] = acc;
}

extern "C" void kernel_launch(void* const* d_in, const int* in_sizes, int n_in,
                              void* d_out, int out_size, void* d_ws, size_t ws_size,
                              hipStream_t stream) {
    const float* W       = (const float*)d_in[0];
    const int*   offsets = (const int*)d_in[1];
    const int*   indices = (const int*)d_in[2];
    float*       out     = (float*)d_out;

    if (ws_size < WS_NEED) {
        pool_fallback_kernel<<<NUM_TABLES * 2048, 256, 0, stream>>>(W, offsets, indices, out);
        return;
    }

    float*    partial = (float*)((char*)d_ws + WS_PART);
    unsigned* sorted  = (unsigned*)((char*)d_ws + WS_SORT);
    unsigned* seg     = (unsigned*)((char*)d_ws + WS_SEG);
    unsigned* hist    = (unsigned*)((char*)d_ws + WS_HIST);
    unsigned* bb      = (unsigned*)((char*)d_ws + WS_BB);
    unsigned* cntb    = (unsigned*)((char*)d_ws + WS_CNTB);

    hist_kernel<<<(NUM_TABLES * NCHUNK) / 4, 256, 0, stream>>>(indices, offsets, hist, seg);
    scan_kernel<<<NUM_TABLES, 64, 0, stream>>>(hist, bb, cntb);
    scatter_kernel<<<(NUM_TABLES * NCHUNK) / 4, 256, 0, stream>>>(indices, seg, hist, bb, sorted);
    finesort_kernel<<<NUM_TABLES * NPASS, 256, 0, stream>>>(sorted, bb, cntb);
    gather_kernel<<<NPG * NUM_TABLES * NUM_TASKS, 1024, 0, stream>>>(W, sorted, bb, cntb, partial);
    reduce_kernel<<<(NUM_TASKS * BATCH) / 256, 256, 0, stream>>>(partial, out);
}